// Round 3
// baseline (1031.306 us; speedup 1.0000x reference)
//
#include <hip/hip_runtime.h>
#include <cstddef>
#include <cstdint>

#define B_    2
#define S_    2048
#define DIN_  1024
#define H_    16
#define DK_   1024
#define DV_   1024
#define DH_   64
#define DOUT_ 1024
#define M_    (B_ * S_)

typedef __attribute__((ext_vector_type(8)))  short short8;
typedef __attribute__((ext_vector_type(4)))  float float4v;
typedef __attribute__((ext_vector_type(16))) float float16v;

__device__ __forceinline__ float bf16s_to_f(short s) {
  union { unsigned int u; float f; } cv;
  cv.u = ((unsigned int)(unsigned short)s) << 16;
  return cv.f;
}
__device__ __forceinline__ short f_to_bf16s(float f) {
  union { float f; unsigned int u; } cv;
  cv.f = f;
  unsigned int u = cv.u + 0x7FFFu + ((cv.u >> 16) & 1u);
  return (short)(u >> 16);
}
// (bf16(hi)<<16) | bf16(lo), truncating — 1 v_perm_b32
__device__ __forceinline__ unsigned pack2bf(float hi, float lo) {
  union { float f; unsigned u; } a, b;
  a.f = hi; b.f = lo;
  return __builtin_amdgcn_perm(a.u, b.u, 0x07060302u);
}

// ---------------- cast f32 -> bf16 (4 elems/thread) ----------------
__global__ __launch_bounds__(256) void cast_kernel(const float* __restrict__ in,
                                                   short* __restrict__ out, int n4) {
  int i = blockIdx.x * 256 + threadIdx.x;
  if (i >= n4) return;
  float4 v = ((const float4*)in)[i];
  union { ushort4 u; short s[4]; } o;
  o.s[0] = f_to_bf16s(v.x); o.s[1] = f_to_bf16s(v.y);
  o.s[2] = f_to_bf16s(v.z); o.s[3] = f_to_bf16s(v.w);
  ((ushort4*)out)[i] = o.u;
}

// ---------------- content bias: CBs[b,h,s] = SC*dot(x[b,s,:],Wcb[h,:]) ----
__global__ __launch_bounds__(256) void cb_kernel(const float* __restrict__ x,
                                                 const float* __restrict__ Wcb,
                                                 float* __restrict__ CBs) {
  __shared__ float xs[DIN_];
  const int row = blockIdx.x;  // b*S + s
  const int tid = threadIdx.x;
  #pragma unroll
  for (int it = 0; it < 4; ++it)
    xs[tid + it * 256] = x[(size_t)row * DIN_ + tid + it * 256];
  __syncthreads();
  const int lane = tid & 63, w = tid >> 6;
  const float SC = 0.125f * 1.44269504088896f;
  #pragma unroll
  for (int hh = 0; hh < 4; ++hh) {
    const int hidx = w * 4 + hh;
    float p = 0.f;
    for (int c = lane; c < DIN_; c += 64)
      p += xs[c] * Wcb[(size_t)hidx * DIN_ + c];
    #pragma unroll
    for (int mk = 1; mk < 64; mk <<= 1) p += __shfl_xor(p, mk);
    if (lane == 0) {
      const int bb = row / S_, ss = row % S_;
      CBs[((size_t)bb * H_ + hidx) * S_ + ss] = p * SC;
    }
  }
}

// ---------------- bf16 NT GEMM: C[M,1024] = A[M,1024] * Bw[1024,1024]^T ----------
// mode 0: outb=bf16(acc); mode 1: outb=bf16(acc+bias); mode 2: outf=acc+bias+resid
// mode 3: transposed-bf16 store: outb is Vt_g[b][col][s], value = acc+bias
__global__ __launch_bounds__(256, 2) void gemm_nt(
    const short* __restrict__ A, const short* __restrict__ Bw,
    const float* __restrict__ bias, const float* __restrict__ resid,
    short* __restrict__ outb, float* __restrict__ outf, int mode) {
  const int KD = 1024, ND = 1024;
  __shared__ short As[64][72];
  __shared__ short Bs[64][72];
  const int tid  = threadIdx.x;
  const int lane = tid & 63;
  const int w    = tid >> 6;
  const int quad = lane >> 4;
  const int l16  = lane & 15;
  const int m0   = blockIdx.y * 64;
  const int n0   = blockIdx.x * 64;
  const int wm   = (w >> 1) * 32;
  const int wn   = (w & 1) * 32;

  const float4v zero = {0.f, 0.f, 0.f, 0.f};
  float4v acc[2][2];
  acc[0][0] = zero; acc[0][1] = zero; acc[1][0] = zero; acc[1][1] = zero;

  for (int k0 = 0; k0 < KD; k0 += 64) {
    __syncthreads();
    #pragma unroll
    for (int it = 0; it < 2; ++it) {
      int idx = tid + it * 256;
      int row = idx >> 3, seg = idx & 7;
      *(short8*)&As[row][seg * 8] =
          *(const short8*)(A + (size_t)(m0 + row) * KD + k0 + seg * 8);
      *(short8*)&Bs[row][seg * 8] =
          *(const short8*)(Bw + (size_t)(n0 + row) * KD + k0 + seg * 8);
    }
    __syncthreads();
    #pragma unroll
    for (int ks = 0; ks < 2; ++ks) {
      short8 af0 = *(short8*)&As[wm + l16][ks * 32 + quad * 8];
      short8 af1 = *(short8*)&As[wm + 16 + l16][ks * 32 + quad * 8];
      short8 bg0 = *(short8*)&Bs[wn + l16][ks * 32 + quad * 8];
      short8 bg1 = *(short8*)&Bs[wn + 16 + l16][ks * 32 + quad * 8];
      acc[0][0] = __builtin_amdgcn_mfma_f32_16x16x32_bf16(af0, bg0, acc[0][0], 0, 0, 0);
      acc[0][1] = __builtin_amdgcn_mfma_f32_16x16x32_bf16(af0, bg1, acc[0][1], 0, 0, 0);
      acc[1][0] = __builtin_amdgcn_mfma_f32_16x16x32_bf16(af1, bg0, acc[1][0], 0, 0, 0);
      acc[1][1] = __builtin_amdgcn_mfma_f32_16x16x32_bf16(af1, bg1, acc[1][1], 0, 0, 0);
    }
  }

  #pragma unroll
  for (int mt = 0; mt < 2; ++mt)
    #pragma unroll
    for (int nt = 0; nt < 2; ++nt)
      #pragma unroll
      for (int r = 0; r < 4; ++r) {
        int row = m0 + wm + mt * 16 + quad * 4 + r;
        int col = n0 + wn + nt * 16 + l16;
        float v = acc[mt][nt][r];
        if (mode >= 1) v += bias[col];
        if (mode == 2)
          outf[(size_t)row * ND + col] = v + resid[(size_t)row * ND + col];
        else if (mode == 3) {
          int bb = row >> 11, ss = row & 2047;
          outb[((size_t)bb * DV_ + col) * S_ + ss] = f_to_bf16s(v);
        } else
          outb[(size_t)row * ND + col] = f_to_bf16s(v);
      }
}

// ---------------- fused collaborative attention v3 ----------------
// Head-PAIR per block: K A-fragments (head-independent) feed 2 MFMAs each.
// Block: 64 queries x 2 heads, 2 waves (128 thr); wave w owns queries
// [i0+32w, i0+32w+32) for BOTH heads. Grid (S/64, H/2, B) = 512 blocks
// -> 4 blocks/CU, 8 waves/CU. S^T formulation (rows=keys, cols=queries),
// lane-local online softmax, P^T reg->B-frag reshape via shfl_xor(32).
__global__ __launch_bounds__(128, 2) void attn_kernel(
    const short* __restrict__ Qb, const short* __restrict__ Kb,
    const short* __restrict__ Vtg, const float* __restrict__ mixing,
    const float* __restrict__ CBs, short* __restrict__ ctxb) {
  __shared__ __align__(16) short Ks[64][136];    // 64 keys x 128-k chunk
  __shared__ __align__(16) short Vt[2][64][72];  // per head: [dv][j]
  __shared__ __align__(16) short mix_s[2][DK_];  // bf16(mix*SC)
  __shared__ float cb_s[2][64];

  const int tid = threadIdx.x;
  const int lane = tid & 63;
  const int l32 = lane & 31;
  const int l1  = lane >> 5;
  const int w   = tid >> 6;       // 0..1
  const int i0  = blockIdx.x * 64;
  const int h0  = blockIdx.y * 2;
  const int b   = blockIdx.z;

  const float SC = 0.125f * 1.44269504088896f;
  for (int c = tid; c < 2 * DK_; c += 128)
    mix_s[c >> 10][c & 1023] = f_to_bf16s(mixing[(size_t)(h0 + (c >> 10)) * DK_ + (c & 1023)] * SC);

  const int iq = i0 + w * 32 + l32;
  const short* qptr  = Qb + ((size_t)b * S_ + iq) * DK_;
  const short* kbase = Kb + (size_t)b * S_ * DK_;
  const short* vtb0  = Vtg + ((size_t)b * DV_ + (h0 + 0) * DH_) * S_;
  const short* vtb1  = Vtg + ((size_t)b * DV_ + (h0 + 1) * DH_) * S_;
  const float* cbp0  = CBs + ((size_t)b * H_ + h0 + 0) * S_;
  const float* cbp1  = CBs + ((size_t)b * H_ + h0 + 1) * S_;

  float16v accO[2][2];
  #pragma unroll
  for (int hh = 0; hh < 2; ++hh)
    #pragma unroll
    for (int g = 0; g < 2; ++g)
      #pragma unroll
      for (int r = 0; r < 16; ++r) accO[hh][g][r] = 0.f;
  float m_run[2] = {-1e30f, -1e30f};
  float l_run[2] = {0.f, 0.f};

  const int krow = tid >> 1;           // K stage: 64 rows, 2 thr/row (256B)
  const int koff = (tid & 1) * 64;

  for (int j0 = 0; j0 < S_; j0 += 64) {
    // ---- stage V^T (both heads) + content bias, own barrier ----
    {
      short8 vreg[8];
      #pragma unroll
      for (int it = 0; it < 8; ++it) {
        const int row = (it & 3) * 16 + (tid >> 3);
        const int col8 = tid & 7;
        const short* src = (it < 4 ? vtb0 : vtb1);
        vreg[it] = *(const short8*)(src + (size_t)row * S_ + j0 + col8 * 8);
      }
      const int cbh = tid >> 6, cbj = tid & 63;
      const float cbv = (cbh ? cbp1 : cbp0)[j0 + cbj];
      __syncthreads();   // prev iter's Vt/cb consumers done
      #pragma unroll
      for (int it = 0; it < 8; ++it) {
        const int row = (it & 3) * 16 + (tid >> 3);
        const int col8 = tid & 7;
        *(short8*)&Vt[it >> 2][row][col8 * 8] = vreg[it];
      }
      cb_s[cbh][cbj] = cbv;
    }

    float16v accS[2][2];
    #pragma unroll
    for (int hh = 0; hh < 2; ++hh)
      #pragma unroll
      for (int f = 0; f < 2; ++f)
        #pragma unroll
        for (int r = 0; r < 16; ++r) accS[hh][f][r] = 0.f;

    for (int kc = 0; kc < 8; ++kc) {
      short8 qraw[8];
      #pragma unroll
      for (int ks = 0; ks < 8; ++ks)
        qraw[ks] = *(const short8*)(qptr + kc * 128 + ks * 16 + l1 * 8);
      short8 kreg[8];
      #pragma unroll
      for (int it = 0; it < 8; ++it)
        kreg[it] = *(const short8*)(kbase + (size_t)(j0 + krow) * DK_ +
                                    kc * 128 + koff + it * 8);
      __syncthreads();   // prev kc's Ks consumers done
      #pragma unroll
      for (int it = 0; it < 8; ++it)
        *(short8*)&Ks[krow][koff + it * 8] = kreg[it];
      __syncthreads();

      #pragma unroll
      for (int ks = 0; ks < 8; ++ks) {
        short8 mf0 = *(short8*)&mix_s[0][kc * 128 + ks * 16 + l1 * 8];
        short8 mf1 = *(short8*)&mix_s[1][kc * 128 + ks * 16 + l1 * 8];
        float qf[8];
        #pragma unroll
        for (int e = 0; e < 8; ++e) qf[e] = bf16s_to_f(qraw[ks][e]);
        union { short8 s; unsigned u[4]; } q0, q1;
        #pragma unroll
        for (int d = 0; d < 4; ++d) {
          q0.u[d] = pack2bf(qf[2 * d + 1] * bf16s_to_f(mf0[2 * d + 1]),
                            qf[2 * d]     * bf16s_to_f(mf0[2 * d]));
          q1.u[d] = pack2bf(qf[2 * d + 1] * bf16s_to_f(mf1[2 * d + 1]),
                            qf[2 * d]     * bf16s_to_f(mf1[2 * d]));
        }
        short8 af0 = *(short8*)&Ks[l32][ks * 16 + l1 * 8];
        short8 af1 = *(short8*)&Ks[32 + l32][ks * 16 + l1 * 8];
        accS[0][0] = __builtin_amdgcn_mfma_f32_32x32x16_bf16(af0, q0.s, accS[0][0], 0, 0, 0);
        accS[1][0] = __builtin_amdgcn_mfma_f32_32x32x16_bf16(af0, q1.s, accS[1][0], 0, 0, 0);
        accS[0][1] = __builtin_amdgcn_mfma_f32_32x32x16_bf16(af1, q0.s, accS[0][1], 0, 0, 0);
        accS[1][1] = __builtin_amdgcn_mfma_f32_32x32x16_bf16(af1, q1.s, accS[1][1], 0, 0, 0);
      }
    }

    // ---- online softmax + PV, per head ----
    #pragma unroll
    for (int hh = 0; hh < 2; ++hh) {
      float tmax = -1e30f;
      #pragma unroll
      for (int f = 0; f < 2; ++f)
        #pragma unroll
        for (int q = 0; q < 4; ++q) {
          float4 cbv = *(float4*)&cb_s[hh][f * 32 + q * 8 + l1 * 4];
          #pragma unroll
          for (int c = 0; c < 4; ++c) {
            accS[hh][f][4 * q + c] += ((const float*)&cbv)[c];
            tmax = fmaxf(tmax, accS[hh][f][4 * q + c]);
          }
        }
      tmax = fmaxf(tmax, __shfl_xor(tmax, 32));
      const float mnew = fmaxf(m_run[hh], tmax);
      const float alpha = exp2f(m_run[hh] - mnew);
      float tsum = 0.f;
      #pragma unroll
      for (int f = 0; f < 2; ++f)
        #pragma unroll
        for (int r = 0; r < 16; ++r) {
          float pv = exp2f(accS[hh][f][r] - mnew);
          accS[hh][f][r] = pv;
          tsum += pv;
        }
      tsum += __shfl_xor(tsum, 32);
      l_run[hh] = l_run[hh] * alpha + tsum;
      m_run[hh] = mnew;
      #pragma unroll
      for (int g = 0; g < 2; ++g)
        #pragma unroll
        for (int r = 0; r < 16; ++r) accO[hh][g][r] *= alpha;

      // P^T reg->B-frag reshape + PV MFMAs
      #pragma unroll
      for (int cpv = 0; cpv < 4; ++cpv) {
        const int t = cpv & 1, fp = cpv >> 1;
        float xo[4], yo[4], lo[4], hi[4];
        #pragma unroll
        for (int c = 0; c < 4; ++c) {
          xo[c] = __shfl_xor(accS[hh][fp][8 * t + c], 32);
          yo[c] = __shfl_xor(accS[hh][fp][8 * t + 4 + c], 32);
        }
        #pragma unroll
        for (int c = 0; c < 4; ++c) {
          lo[c] = l1 ? yo[c] : accS[hh][fp][8 * t + c];
          hi[c] = l1 ? accS[hh][fp][8 * t + 4 + c] : xo[c];
        }
        union { short8 s; unsigned u[4]; } pb;
        pb.u[0] = pack2bf(lo[1], lo[0]);
        pb.u[1] = pack2bf(lo[3], lo[2]);
        pb.u[2] = pack2bf(hi[1], hi[0]);
        pb.u[3] = pack2bf(hi[3], hi[2]);
        #pragma unroll
        for (int g = 0; g < 2; ++g) {
          short8 vf = *(short8*)&Vt[hh][g * 32 + l32][cpv * 16 + l1 * 8];
          accO[hh][g] = __builtin_amdgcn_mfma_f32_32x32x16_bf16(vf, pb.s, accO[hh][g], 0, 0, 0);
        }
      }
    }
  }

  // ---- epilogue: normalize, store ctx ----
  #pragma unroll
  for (int hh = 0; hh < 2; ++hh) {
    const float rl = 1.0f / l_run[hh];
    short* cbase = ctxb + ((size_t)b * S_ + iq) * DV_ + (h0 + hh) * DH_;
    #pragma unroll
    for (int g = 0; g < 2; ++g)
      #pragma unroll
      for (int q = 0; q < 4; ++q) {
        const int dv = g * 32 + 8 * q + 4 * l1;
        union { ushort4 u4; short s[4]; } ov;
        #pragma unroll
        for (int r = 0; r < 4; ++r)
          ov.s[r] = f_to_bf16s(accO[hh][g][4 * q + r] * rl);
        *(ushort4*)(cbase + dv) = ov.u4;
      }
  }
}

// ---------------- LayerNorm in-place on d_out ----------------
__global__ __launch_bounds__(256) void ln_kernel(float* __restrict__ out,
                                                 const float* __restrict__ gamma,
                                                 const float* __restrict__ beta) {
  __shared__ float red[8];
  const int row = blockIdx.x;
  const int tid = threadIdx.x;
  float* p = out + (size_t)row * DOUT_;
  float4 v = ((const float4*)p)[tid];
  float s = v.x + v.y + v.z + v.w;
  #pragma unroll
  for (int mk = 1; mk < 64; mk <<= 1) s += __shfl_xor(s, mk);
  if ((tid & 63) == 0) red[tid >> 6] = s;
  __syncthreads();
  const float mean = (red[0] + red[1] + red[2] + red[3]) * (1.0f / 1024.0f);
  const float d0 = v.x - mean, d1 = v.y - mean, d2 = v.z - mean, d3 = v.w - mean;
  float sq = d0 * d0 + d1 * d1 + d2 * d2 + d3 * d3;
  #pragma unroll
  for (int mk = 1; mk < 64; mk <<= 1) sq += __shfl_xor(sq, mk);
  if ((tid & 63) == 0) red[4 + (tid >> 6)] = sq;
  __syncthreads();
  const float var = (red[4] + red[5] + red[6] + red[7]) * (1.0f / 1024.0f);
  const float rstd = rsqrtf(var + 1e-5f);
  float4 g = ((const float4*)gamma)[tid];
  float4 bt = ((const float4*)beta)[tid];
  float4 o;
  o.x = d0 * rstd * g.x + bt.x;
  o.y = d1 * rstd * g.y + bt.y;
  o.z = d2 * rstd * g.z + bt.z;
  o.w = d3 * rstd * g.w + bt.w;
  ((float4*)p)[tid] = o;
}

extern "C" void kernel_launch(void* const* d_in, const int* in_sizes, int n_in,
                              void* d_out, int out_size, void* d_ws, size_t ws_size,
                              hipStream_t stream) {
  (void)in_sizes; (void)n_in; (void)out_size; (void)ws_size;
  const float* x      = (const float*)d_in[0];
  const float* Wq     = (const float*)d_in[1];
  const float* Wk     = (const float*)d_in[2];
  const float* Wcb    = (const float*)d_in[3];
  const float* Wv     = (const float*)d_in[4];
  const float* bv     = (const float*)d_in[5];
  const float* mixing = (const float*)d_in[6];
  const float* Wd     = (const float*)d_in[7];
  const float* bd     = (const float*)d_in[8];
  const float* gamma  = (const float*)d_in[9];
  const float* beta   = (const float*)d_in[10];
  float* out = (float*)d_out;

  short* p = (short*)d_ws;
  short* xb   = p; p += (size_t)M_ * DIN_;
  short* Qb   = p; p += (size_t)M_ * DK_;
  short* Kb   = p; p += (size_t)M_ * DK_;
  short* Vtg  = p; p += (size_t)B_ * DV_ * S_;   // V^T: [b][dv][s]
  short* ctxb = p; p += (size_t)M_ * DV_;
  short* Wqb  = p; p += (size_t)DK_ * DIN_;
  short* Wkb  = p; p += (size_t)DK_ * DIN_;
  short* Wvb  = p; p += (size_t)DV_ * DIN_;
  short* Wdb  = p; p += (size_t)DOUT_ * DV_;
  float* CBs  = (float*)p;   // B*H*S floats

  cast_kernel<<<dim3(M_ * DIN_ / 1024), 256, 0, stream>>>(x, xb, M_ * DIN_ / 4);
  cast_kernel<<<dim3(DK_ * DIN_ / 1024), 256, 0, stream>>>(Wq, Wqb, DK_ * DIN_ / 4);
  cast_kernel<<<dim3(DK_ * DIN_ / 1024), 256, 0, stream>>>(Wk, Wkb, DK_ * DIN_ / 4);
  cast_kernel<<<dim3(DV_ * DIN_ / 1024), 256, 0, stream>>>(Wv, Wvb, DV_ * DIN_ / 4);
  cast_kernel<<<dim3(DOUT_ * DV_ / 1024), 256, 0, stream>>>(Wd, Wdb, DOUT_ * DV_ / 4);
  cb_kernel<<<dim3(M_), 256, 0, stream>>>(x, Wcb, CBs);

  dim3 gg(DOUT_ / 64, M_ / 64);
  gemm_nt<<<gg, 256, 0, stream>>>(xb, Wqb, nullptr, nullptr, Qb, nullptr, 0);
  gemm_nt<<<gg, 256, 0, stream>>>(xb, Wkb, nullptr, nullptr, Kb, nullptr, 0);
  gemm_nt<<<gg, 256, 0, stream>>>(xb, Wvb, bv, nullptr, Vtg, nullptr, 3);  // V^T + bias

  attn_kernel<<<dim3(S_ / 64, H_ / 2, B_), 128, 0, stream>>>(Qb, Kb, Vtg, mixing, CBs, ctxb);

  gemm_nt<<<gg, 256, 0, stream>>>(ctxb, Wdb, bd, x, nullptr, out, 2);
  ln_kernel<<<dim3(M_), 256, 0, stream>>>(out, gamma, beta);
}

// Round 5
// 648.434 us; speedup vs baseline: 1.5905x; 1.5905x over previous
//
#include <hip/hip_runtime.h>
#include <cstddef>
#include <cstdint>

#define B_    2
#define S_    2048
#define DIN_  1024
#define H_    16
#define DK_   1024
#define DV_   1024
#define DH_   64
#define DOUT_ 1024
#define M_    (B_ * S_)

typedef __attribute__((ext_vector_type(8)))  short short8;
typedef __attribute__((ext_vector_type(4)))  float float4v;
typedef __attribute__((ext_vector_type(16))) float float16v;
typedef _Float16 half8v __attribute__((ext_vector_type(8)));

__device__ __forceinline__ float bf16s_to_f(short s) {
  union { unsigned int u; float f; } cv;
  cv.u = ((unsigned int)(unsigned short)s) << 16;
  return cv.f;
}
__device__ __forceinline__ short f_to_bf16s(float f) {
  union { float f; unsigned int u; } cv;
  cv.f = f;
  unsigned int u = cv.u + 0x7FFFu + ((cv.u >> 16) & 1u);
  return (short)(u >> 16);
}
__device__ __forceinline__ short f_to_f16s(float f) {
  union { _Float16 h; short s; } cv;
  cv.h = (_Float16)f;
  return cv.s;
}
// packed f32x2 -> f16x2 (v_cvt_pkrtz_f16_f32), returned as a raw 32-bit word
__device__ __forceinline__ unsigned pkrtz_u32(float a, float b) {
  union { __fp16 __attribute__((ext_vector_type(2))) h2; unsigned u; } cv;
  cv.h2 = __builtin_amdgcn_cvt_pkrtz(a, b);   // [0]=a, [1]=b
  return cv.u;
}
__device__ __forceinline__ void gll16(const void* g, void* l) {
  __builtin_amdgcn_global_load_lds(
      (const __attribute__((address_space(1))) unsigned int*)g,
      (__attribute__((address_space(3))) unsigned int*)l, 16, 0, 0);
}

// ---------------- cast f32 -> bf16 (4 elems/thread) ----------------
__global__ __launch_bounds__(256) void cast_kernel(const float* __restrict__ in,
                                                   short* __restrict__ out, int n4) {
  int i = blockIdx.x * 256 + threadIdx.x;
  if (i >= n4) return;
  float4 v = ((const float4*)in)[i];
  union { ushort4 u; short s[4]; } o;
  o.s[0] = f_to_bf16s(v.x); o.s[1] = f_to_bf16s(v.y);
  o.s[2] = f_to_bf16s(v.z); o.s[3] = f_to_bf16s(v.w);
  ((ushort4*)out)[i] = o.u;
}

// ---------------- content bias: CBs[b,h,s] = SC*dot(x[b,s,:],Wcb[h,:]) ----
__global__ __launch_bounds__(256) void cb_kernel(const float* __restrict__ x,
                                                 const float* __restrict__ Wcb,
                                                 float* __restrict__ CBs) {
  __shared__ float xs[DIN_];
  const int row = blockIdx.x;  // b*S + s
  const int tid = threadIdx.x;
  #pragma unroll
  for (int it = 0; it < 4; ++it)
    xs[tid + it * 256] = x[(size_t)row * DIN_ + tid + it * 256];
  __syncthreads();
  const int lane = tid & 63, w = tid >> 6;
  const float SC = 0.125f * 1.44269504088896f;
  #pragma unroll
  for (int hh = 0; hh < 4; ++hh) {
    const int hidx = w * 4 + hh;
    float p = 0.f;
    for (int c = lane; c < DIN_; c += 64)
      p += xs[c] * Wcb[(size_t)hidx * DIN_ + c];
    #pragma unroll
    for (int mk = 1; mk < 64; mk <<= 1) p += __shfl_xor(p, mk);
    if (lane == 0) {
      const int bb = row / S_, ss = row % S_;
      CBs[((size_t)bb * H_ + hidx) * S_ + ss] = p * SC;
    }
  }
}

// ---------------- bf16 NT GEMM: C[M,1024] = A[M,1024] * Bw[1024,1024]^T ----------
// BK=128 (2 barriers per 128-k). modes: 0 bf16; 1 bf16+bias; 2 f32+bias+resid;
// 4 f16; 5 f16 transposed ([b][col][s]) + bias
__global__ __launch_bounds__(256, 2) void gemm_nt(
    const short* __restrict__ A, const short* __restrict__ Bw,
    const float* __restrict__ bias, const float* __restrict__ resid,
    short* __restrict__ outb, float* __restrict__ outf, int mode) {
  const int KD = 1024, ND = 1024;
  __shared__ short As[64][136];
  __shared__ short Bs[64][136];
  const int tid  = threadIdx.x;
  const int lane = tid & 63;
  const int w    = tid >> 6;
  const int quad = lane >> 4;
  const int l16  = lane & 15;
  const int m0   = blockIdx.y * 64;
  const int n0   = blockIdx.x * 64;
  const int wm   = (w >> 1) * 32;
  const int wn   = (w & 1) * 32;
  const int srow = tid >> 2;        // staging: 64 rows, 4 thr/row (256B)
  const int sseg = (tid & 3) * 32;

  const float4v zero = {0.f, 0.f, 0.f, 0.f};
  float4v acc[2][2];
  acc[0][0] = zero; acc[0][1] = zero; acc[1][0] = zero; acc[1][1] = zero;

  for (int k0 = 0; k0 < KD; k0 += 128) {
    short8 ar[4], br[4];
    #pragma unroll
    for (int c = 0; c < 4; ++c) {
      ar[c] = *(const short8*)(A  + (size_t)(m0 + srow) * KD + k0 + sseg + c * 8);
      br[c] = *(const short8*)(Bw + (size_t)(n0 + srow) * KD + k0 + sseg + c * 8);
    }
    __syncthreads();
    #pragma unroll
    for (int c = 0; c < 4; ++c) {
      *(short8*)&As[srow][sseg + c * 8] = ar[c];
      *(short8*)&Bs[srow][sseg + c * 8] = br[c];
    }
    __syncthreads();
    #pragma unroll
    for (int ks = 0; ks < 4; ++ks) {
      short8 af0 = *(short8*)&As[wm + l16][ks * 32 + quad * 8];
      short8 af1 = *(short8*)&As[wm + 16 + l16][ks * 32 + quad * 8];
      short8 bg0 = *(short8*)&Bs[wn + l16][ks * 32 + quad * 8];
      short8 bg1 = *(short8*)&Bs[wn + 16 + l16][ks * 32 + quad * 8];
      acc[0][0] = __builtin_amdgcn_mfma_f32_16x16x32_bf16(af0, bg0, acc[0][0], 0, 0, 0);
      acc[0][1] = __builtin_amdgcn_mfma_f32_16x16x32_bf16(af0, bg1, acc[0][1], 0, 0, 0);
      acc[1][0] = __builtin_amdgcn_mfma_f32_16x16x32_bf16(af1, bg0, acc[1][0], 0, 0, 0);
      acc[1][1] = __builtin_amdgcn_mfma_f32_16x16x32_bf16(af1, bg1, acc[1][1], 0, 0, 0);
    }
  }

  #pragma unroll
  for (int mt = 0; mt < 2; ++mt)
    #pragma unroll
    for (int nt = 0; nt < 2; ++nt)
      #pragma unroll
      for (int r = 0; r < 4; ++r) {
        int row = m0 + wm + mt * 16 + quad * 4 + r;   // verified C/D layout
        int col = n0 + wn + nt * 16 + l16;
        float v = acc[mt][nt][r];
        if (mode == 1 || mode == 5) v += bias[col];
        if (mode == 2)
          outf[(size_t)row * ND + col] = v + bias[col] + resid[(size_t)row * ND + col];
        else if (mode == 5) {
          int bb = row >> 11, ss = row & 2047;
          outb[((size_t)bb * DV_ + col) * S_ + ss] = f_to_f16s(v);
        } else if (mode == 4)
          outb[(size_t)row * ND + col] = f_to_f16s(v);
        else
          outb[(size_t)row * ND + col] = f_to_bf16s(v);
      }
}

// ---------------- fused collaborative attention v4 (f16) ----------------
// Round-2 skeleton: 128 queries x 1 head per block, 4 waves, S^T via
// 32x32x16 f16 MFMA, lane-local online softmax, reg P^T reshape.
// New: f16 operands + v_pk_mul_f16 qm build; K staged by global_load_lds
// into XOR-swizzled unpadded LDS (phys chunk p = c16 ^ (row&15));
// XCD-locality block remap (resident blocks share one batch's K).
__global__ __launch_bounds__(256, 2) void attn_kernel(
    const short* __restrict__ Qf, const short* __restrict__ Kf,
    const short* __restrict__ Vtf, const float* __restrict__ mixing,
    const float* __restrict__ CBs, short* __restrict__ ctxb) {
  __shared__ __align__(16) short KsF[128 * 128];   // swizzled, 32 KB
  __shared__ __align__(16) short Vt[64][136];      // V^T tile [dv][j], f16
  __shared__ __align__(16) short mix_s[DK_];       // f16(mix*SC)
  __shared__ float cb_s[128];

  const int tid  = threadIdx.x;
  const int lane = tid & 63;
  const int l32  = lane & 31;
  const int l1   = lane >> 5;
  const int w    = tid >> 6;

  // XCD-locality remap: xcd class = blk&7; b per xcd-half, 4 heads per xcd
  const int F    = blockIdx.x;
  const int xcd  = F & 7, rest = F >> 3;
  const int b    = xcd >> 2;
  const int h    = (xcd & 3) * 4 + (rest & 3);
  const int i0   = (rest >> 2) * 128;

  const float SC = 0.125f * 1.44269504088896f;
  for (int c = tid; c < DK_; c += 256) {
    union { _Float16 h; short s; } cv;
    cv.h = (_Float16)(mixing[(size_t)h * DK_ + c] * SC);
    mix_s[c] = cv.s;
  }

  const int iq = i0 + w * 32 + l32;
  const short* qptr  = Qf + ((size_t)b * S_ + iq) * DK_;
  const short* kbase = Kf + (size_t)b * S_ * DK_;
  const short* vtb   = Vtf + ((size_t)b * DV_ + h * DH_) * S_;
  const float* cbp   = CBs + ((size_t)b * H_ + h) * S_;

  float16v accS[4], accO[2];
  #pragma unroll
  for (int g = 0; g < 2; ++g)
    #pragma unroll
    for (int r = 0; r < 16; ++r) accO[g][r] = 0.f;
  float m_run = -1e30f, l_run = 0.f;

  // K DMA source offsets: call n (= w*8+cc): lane covers row r=4n+(lane>>4),
  // phys chunk p=lane&15 holds logical chunk l=p^(r&15)
  const int drow_l = lane >> 4;          // 0..3 within call
  const int dp     = lane & 15;

  const int vrow = tid >> 2;             // Vt stage: 64 rows, 4 thr/row
  const int vseg = (tid & 3) * 32;

  for (int j0 = 0; j0 < S_; j0 += 128) {
    // ---- stage V^T + cb (reg round-trip, padded LDS) ----
    short8 vreg[4];
    #pragma unroll
    for (int c = 0; c < 4; ++c)
      vreg[c] = *(const short8*)(vtb + (size_t)vrow * S_ + j0 + vseg + c * 8);
    float cbv = 0.f;
    if (tid < 128) cbv = cbp[j0 + tid];
    __syncthreads();   // prev j-tile's Vt/cb consumers done
    #pragma unroll
    for (int c = 0; c < 4; ++c)
      *(short8*)&Vt[vrow][vseg + c * 8] = vreg[c];
    if (tid < 128) cb_s[tid] = cbv;

    #pragma unroll
    for (int f = 0; f < 4; ++f)
      #pragma unroll
      for (int r = 0; r < 16; ++r) accS[f][r] = 0.f;

    for (int kc = 0; kc < 8; ++kc) {
      // Q fragment loads (L1-hot re-reads)
      half8v qraw[8];
      #pragma unroll
      for (int ks = 0; ks < 8; ++ks)
        qraw[ks] = *(const half8v*)(qptr + kc * 128 + ks * 16 + l1 * 8);
      __syncthreads();   // prev kc's Ks consumers done (kc==0: Vt writes visible)
      // ---- K tile 128x128 via global_load_lds, swizzled ----
      #pragma unroll
      for (int cc = 0; cc < 8; ++cc) {
        const int n = w * 8 + cc;
        const int r = 4 * n + drow_l;
        const int lchunk = dp ^ (r & 15);
        gll16(kbase + (size_t)(j0 + r) * DK_ + kc * 128 + lchunk * 8,
              &KsF[n * 512]);
      }
      __syncthreads();   // drains vmcnt -> K tile ready

      #pragma unroll
      for (int ks = 0; ks < 8; ++ks) {
        half8v mf = *(half8v*)&mix_s[kc * 128 + ks * 16 + l1 * 8];
        half8v qm = qraw[ks] * mf;                    // 4x v_pk_mul_f16
        const int poff = ((2 * ks + l1) ^ (l32 & 15)) * 8 + l32 * 128;
        #pragma unroll
        for (int f = 0; f < 4; ++f) {
          half8v af = *(half8v*)&KsF[f * 4096 + poff];
          accS[f] = __builtin_amdgcn_mfma_f32_32x32x16_f16(af, qm, accS[f], 0, 0, 0);
        }
      }
    }

    // ---- online softmax: lane-local + 1 shfl ----
    float tmax = -1e30f;
    #pragma unroll
    for (int f = 0; f < 4; ++f)
      #pragma unroll
      for (int q = 0; q < 4; ++q) {
        float4 cbq = *(float4*)&cb_s[f * 32 + q * 8 + l1 * 4];
        #pragma unroll
        for (int c = 0; c < 4; ++c) {
          accS[f][4 * q + c] += ((const float*)&cbq)[c];
          tmax = fmaxf(tmax, accS[f][4 * q + c]);
        }
      }
    tmax = fmaxf(tmax, __shfl_xor(tmax, 32));
    const float mnew = fmaxf(m_run, tmax);
    const float alpha = exp2f(m_run - mnew);
    float tsum = 0.f;
    #pragma unroll
    for (int f = 0; f < 4; ++f)
      #pragma unroll
      for (int r = 0; r < 16; ++r) {
        float pv = exp2f(accS[f][r] - mnew);
        accS[f][r] = pv;
        tsum += pv;
      }
    tsum += __shfl_xor(tsum, 32);
    l_run = l_run * alpha + tsum;
    m_run = mnew;
    #pragma unroll
    for (int g = 0; g < 2; ++g)
      #pragma unroll
      for (int r = 0; r < 16; ++r) accO[g][r] *= alpha;

    // ---- PV: O^T[dv][i] += V^T[dv][j] @ P^T[j][i] ----
    #pragma unroll
    for (int cpv = 0; cpv < 8; ++cpv) {
      const int t = cpv & 1, fp = cpv >> 1;
      float xo[4], yo[4], lo[4], hi[4];
      #pragma unroll
      for (int c = 0; c < 4; ++c) {
        xo[c] = __shfl_xor(accS[fp][8 * t + c], 32);
        yo[c] = __shfl_xor(accS[fp][8 * t + 4 + c], 32);
      }
      #pragma unroll
      for (int c = 0; c < 4; ++c) {
        lo[c] = l1 ? yo[c] : accS[fp][8 * t + c];
        hi[c] = l1 ? accS[fp][8 * t + 4 + c] : xo[c];
      }
      union { half8v v; unsigned u[4]; } pb;
      pb.u[0] = pkrtz_u32(lo[0], lo[1]);
      pb.u[1] = pkrtz_u32(lo[2], lo[3]);
      pb.u[2] = pkrtz_u32(hi[0], hi[1]);
      pb.u[3] = pkrtz_u32(hi[2], hi[3]);
      #pragma unroll
      for (int g = 0; g < 2; ++g) {
        half8v vf = *(half8v*)&Vt[g * 32 + l32][cpv * 16 + l1 * 8];
        accO[g] = __builtin_amdgcn_mfma_f32_32x32x16_f16(vf, pb.v, accO[g], 0, 0, 0);
      }
    }
  }

  // ---- epilogue: normalize, store ctx (bf16) ----
  const float rl = 1.0f / l_run;
  short* cbase = ctxb + ((size_t)b * S_ + iq) * DV_ + h * DH_;
  #pragma unroll
  for (int g = 0; g < 2; ++g)
    #pragma unroll
    for (int q = 0; q < 4; ++q) {
      const int dv = g * 32 + 8 * q + 4 * l1;
      union { ushort4 u4; short s[4]; } ov;
      #pragma unroll
      for (int r = 0; r < 4; ++r)
        ov.s[r] = f_to_bf16s(accO[g][4 * q + r] * rl);
      *(ushort4*)(cbase + dv) = ov.u4;
    }
}

// ---------------- LayerNorm in-place on d_out ----------------
__global__ __launch_bounds__(256) void ln_kernel(float* __restrict__ out,
                                                 const float* __restrict__ gamma,
                                                 const float* __restrict__ beta) {
  __shared__ float red[8];
  const int row = blockIdx.x;
  const int tid = threadIdx.x;
  float* p = out + (size_t)row * DOUT_;
  float4 v = ((const float4*)p)[tid];
  float s = v.x + v.y + v.z + v.w;
  #pragma unroll
  for (int mk = 1; mk < 64; mk <<= 1) s += __shfl_xor(s, mk);
  if ((tid & 63) == 0) red[tid >> 6] = s;
  __syncthreads();
  const float mean = (red[0] + red[1] + red[2] + red[3]) * (1.0f / 1024.0f);
  const float d0 = v.x - mean, d1 = v.y - mean, d2 = v.z - mean, d3 = v.w - mean;
  float sq = d0 * d0 + d1 * d1 + d2 * d2 + d3 * d3;
  #pragma unroll
  for (int mk = 1; mk < 64; mk <<= 1) sq += __shfl_xor(sq, mk);
  if ((tid & 63) == 0) red[4 + (tid >> 6)] = sq;
  __syncthreads();
  const float var = (red[4] + red[5] + red[6] + red[7]) * (1.0f / 1024.0f);
  const float rstd = rsqrtf(var + 1e-5f);
  float4 g = ((const float4*)gamma)[tid];
  float4 bt = ((const float4*)beta)[tid];
  float4 o;
  o.x = d0 * rstd * g.x + bt.x;
  o.y = d1 * rstd * g.y + bt.y;
  o.z = d2 * rstd * g.z + bt.z;
  o.w = d3 * rstd * g.w + bt.w;
  ((float4*)p)[tid] = o;
}

extern "C" void kernel_launch(void* const* d_in, const int* in_sizes, int n_in,
                              void* d_out, int out_size, void* d_ws, size_t ws_size,
                              hipStream_t stream) {
  (void)in_sizes; (void)n_in; (void)out_size; (void)ws_size;
  const float* x      = (const float*)d_in[0];
  const float* Wq     = (const float*)d_in[1];
  const float* Wk     = (const float*)d_in[2];
  const float* Wcb    = (const float*)d_in[3];
  const float* Wv     = (const float*)d_in[4];
  const float* bv     = (const float*)d_in[5];
  const float* mixing = (const float*)d_in[6];
  const float* Wd     = (const float*)d_in[7];
  const float* bd     = (const float*)d_in[8];
  const float* gamma  = (const float*)d_in[9];
  const float* beta   = (const float*)d_in[10];
  float* out = (float*)d_out;

  short* p = (short*)d_ws;
  short* xb   = p; p += (size_t)M_ * DIN_;
  short* Qf   = p; p += (size_t)M_ * DK_;      // f16
  short* Kf   = p; p += (size_t)M_ * DK_;      // f16
  short* Vtf  = p; p += (size_t)B_ * DV_ * S_; // f16, [b][dv][s]
  short* ctxb = p; p += (size_t)M_ * DV_;      // bf16
  short* Wqb  = p; p += (size_t)DK_ * DIN_;
  short* Wkb  = p; p += (size_t)DK_ * DIN_;
  short* Wvb  = p; p += (size_t)DV_ * DIN_;
  short* Wdb  = p; p += (size_t)DOUT_ * DV_;
  float* CBs  = (float*)p;   // B*H*S floats

  cast_kernel<<<dim3(M_ * DIN_ / 1024), 256, 0, stream>>>(x, xb, M_ * DIN_ / 4);
  cast_kernel<<<dim3(DK_ * DIN_ / 1024), 256, 0, stream>>>(Wq, Wqb, DK_ * DIN_ / 4);
  cast_kernel<<<dim3(DK_ * DIN_ / 1024), 256, 0, stream>>>(Wk, Wkb, DK_ * DIN_ / 4);
  cast_kernel<<<dim3(DV_ * DIN_ / 1024), 256, 0, stream>>>(Wv, Wvb, DV_ * DIN_ / 4);
  cast_kernel<<<dim3(DOUT_ * DV_ / 1024), 256, 0, stream>>>(Wd, Wdb, DOUT_ * DV_ / 4);
  cb_kernel<<<dim3(M_), 256, 0, stream>>>(x, Wcb, CBs);

  dim3 gg(DOUT_ / 64, M_ / 64);
  gemm_nt<<<gg, 256, 0, stream>>>(xb, Wqb, nullptr, nullptr, Qf, nullptr, 4);
  gemm_nt<<<gg, 256, 0, stream>>>(xb, Wkb, nullptr, nullptr, Kf, nullptr, 4);
  gemm_nt<<<gg, 256, 0, stream>>>(xb, Wvb, bv, nullptr, Vtf, nullptr, 5);

  attn_kernel<<<dim3(512), 256, 0, stream>>>(Qf, Kf, Vtf, mixing, CBs, ctxb);

  gemm_nt<<<gg, 256, 0, stream>>>(ctxb, Wdb, bd, x, nullptr, out, 2);
  ln_kernel<<<dim3(M_), 256, 0, stream>>>(out, gamma, beta);
}